// Round 1
// baseline (127.859 us; speedup 1.0000x reference)
//
#include <hip/hip_runtime.h>

// COO SpMM: out[r,:] = sum_e vals[e] * seq[cols[e],:] for rows[e]==r
// rows sorted ascending. N=50000 nodes, E=1.25M edges, D=64, fp32.
//
// One wave (64 lanes) per chunk of EPW contiguous edges. Lane = feature index.
// Register accumulator per lane; flush with atomicAdd on row change (rows
// sorted -> ~E/N = 25 edges per row, so flushes are rare). Edge metadata
// loaded 64-wide coalesced, broadcast with __shfl. Gather loads batched 8
// deep for latency hiding.

#define D_FEAT 64
#define EPW 192              // edges per wave (multiple of 64)
#define WAVES_PER_BLOCK 4    // 256-thread blocks

__global__ __launch_bounds__(256) void spmm_coo_kernel(
    const float* __restrict__ seq,   // [N, 64]
    const float* __restrict__ vals,  // [E]
    const int*   __restrict__ rows,  // [E] sorted
    const int*   __restrict__ cols,  // [E]
    float*       __restrict__ out,   // [N, 64], pre-zeroed
    int n_edges)
{
    const int lane = threadIdx.x & 63;
    const int wave = blockIdx.x * WAVES_PER_BLOCK + (threadIdx.x >> 6);

    long long start_ll = (long long)wave * EPW;
    if (start_ll >= n_edges) return;
    const int s     = (int)start_ll;
    const int e_end = min(s + EPW, n_edges);

    int   cur_row = rows[s];   // same address all lanes -> broadcast load
    float acc     = 0.f;

    for (int base = s; base < e_end; base += 64) {
        // coalesced metadata load: one edge per lane
        int   r = 0, c = 0;
        float v = 0.f;
        const int e = base + lane;
        if (e < e_end) {
            r = rows[e];
            c = cols[e];
            v = vals[e];
        }
        const int cnt = min(64, e_end - base);

        int j = 0;
        // main path: batches of 8 edges, gather loads issued up-front so 8
        // independent vmem ops are in flight per wave
        for (; j + 8 <= cnt; j += 8) {
            float x[8];
#pragma unroll
            for (int u = 0; u < 8; ++u) {
                const int cj = __shfl(c, j + u);
                x[u] = seq[cj * D_FEAT + lane];
            }
#pragma unroll
            for (int u = 0; u < 8; ++u) {
                const int   rj = __shfl(r, j + u);
                const float vj = __shfl(v, j + u);
                if (rj != cur_row) {           // wave-uniform branch
                    atomicAdd(&out[cur_row * D_FEAT + lane], acc);
                    cur_row = rj;
                    acc = 0.f;
                }
                acc = fmaf(vj, x[u], acc);
            }
        }
        // remainder (only the final partial chunk of the grid)
        for (; j < cnt; ++j) {
            const int   rj = __shfl(r, j);
            const int   cj = __shfl(c, j);
            const float vj = __shfl(v, j);
            if (rj != cur_row) {
                atomicAdd(&out[cur_row * D_FEAT + lane], acc);
                cur_row = rj;
                acc = 0.f;
            }
            acc = fmaf(vj, seq[cj * D_FEAT + lane], acc);
        }
    }
    atomicAdd(&out[cur_row * D_FEAT + lane], acc);
}

extern "C" void kernel_launch(void* const* d_in, const int* in_sizes, int n_in,
                              void* d_out, int out_size, void* d_ws, size_t ws_size,
                              hipStream_t stream) {
    const float* seq  = (const float*)d_in[0];
    const float* vals = (const float*)d_in[1];
    const int*   rows = (const int*)d_in[2];
    const int*   cols = (const int*)d_in[3];
    float*       out  = (float*)d_out;

    const int n_edges = in_sizes[1];  // vals element count = E

    // out is poisoned 0xAA before every timed call -> must zero every call
    hipMemsetAsync(d_out, 0, (size_t)out_size * sizeof(float), stream);

    const int waves  = (n_edges + EPW - 1) / EPW;
    const int blocks = (waves + WAVES_PER_BLOCK - 1) / WAVES_PER_BLOCK;
    spmm_coo_kernel<<<blocks, 256, 0, stream>>>(seq, vals, rows, cols, out, n_edges);
}